// Round 1
// baseline (680.620 us; speedup 1.0000x reference)
//
#include <hip/hip_runtime.h>
#include <hip/hip_bf16.h>

#define BB 8
#define NN 4096
#define FF 128
#define GS 1024

// ---------------------------------------------------------------------------
// Kernel 1: per-batch top-1024 of x[b, :, 127], sorted descending, ties by
// lower index first (jax.lax.top_k semantics). Full bitonic sort of 4096
// 64-bit keys in LDS. One block per batch, 1024 threads.
// key = (~sortable_asc(value) << 32) | index  -> ascending sort gives
// descending value, ascending index on ties.
// ---------------------------------------------------------------------------
__global__ __launch_bounds__(1024) void topk_kernel(const float* __restrict__ x,
                                                    int* __restrict__ idx) {
    __shared__ unsigned long long keys[NN];   // 32 KB
    const int b = blockIdx.x;
    const float* xb = x + (size_t)b * NN * FF;

    for (int i = threadIdx.x; i < NN; i += 1024) {
        float v = xb[(size_t)i * FF + (FF - 1)];
        unsigned int bits = __float_as_uint(v);
        unsigned int sv = (bits & 0x80000000u) ? ~bits : (bits | 0x80000000u);
        keys[i] = ((unsigned long long)(~sv) << 32) | (unsigned int)i;
    }
    __syncthreads();

    for (int k = 2; k <= NN; k <<= 1) {
        for (int j = k >> 1; j > 0; j >>= 1) {
            for (int e = threadIdx.x; e < NN; e += 1024) {
                int ixj = e ^ j;
                if (ixj > e) {
                    bool asc = ((e & k) == 0);
                    unsigned long long a = keys[e];
                    unsigned long long c = keys[ixj];
                    if ((a > c) == asc) { keys[e] = c; keys[ixj] = a; }
                }
            }
            __syncthreads();
        }
    }
    // fully ascending; first GS entries are the top-GS
    idx[b * GS + threadIdx.x] = (int)(keys[threadIdx.x] & 0xFFFFFFFFu);
}

// ---------------------------------------------------------------------------
// Kernel 2: xg[b, j, :] = x[b, idx[b,j], :]   (128 floats = 32 float4 per row)
// 32 lanes per row, fully coalesced both sides.
// ---------------------------------------------------------------------------
__global__ __launch_bounds__(256) void gatherx_kernel(const float* __restrict__ x,
                                                      const int* __restrict__ idx,
                                                      float* __restrict__ outx) {
    int gid  = blockIdx.x * 256 + threadIdx.x;   // B*GS*32 lanes total
    int lane = gid & 31;
    int row  = gid >> 5;                          // [0, B*GS)
    int b = row >> 10;
    int j = row & (GS - 1);
    int src = idx[b * GS + j];
    const float4* s4 = (const float4*)(x + ((size_t)b * NN + src) * FF);
    float4*       d4 = (float4*)(outx + (size_t)row * FF);
    d4[lane] = s4[lane];
}

// ---------------------------------------------------------------------------
// Kernel 3: At2[b, j, k] = A[b, idx[b,j], idx[b,k]].
// One block per output row: stage the full 4096-float source row in LDS
// (coalesced), gather 1024 columns from LDS, write coalesced float4.
// ---------------------------------------------------------------------------
__global__ __launch_bounds__(256) void gatherA_kernel(const float* __restrict__ A,
                                                      const int* __restrict__ idx,
                                                      float* __restrict__ outA) {
    __shared__ float row[NN];    // 16 KB
    __shared__ int  cols[GS];    //  4 KB
    const int b = blockIdx.x >> 10;
    const int j = blockIdx.x & (GS - 1);
    const int* idxb = idx + b * GS;
    const int srcrow = idxb[j];

    const float4* a4   = (const float4*)(A + ((size_t)b * NN + srcrow) * NN);
    float4*       row4 = (float4*)row;
    for (int i = threadIdx.x; i < NN / 4; i += 256) row4[i] = a4[i];
    for (int i = threadIdx.x; i < GS; i += 256)     cols[i] = idxb[i];
    __syncthreads();

    float4* out4 = (float4*)(outA + (size_t)blockIdx.x * GS);
    for (int i = threadIdx.x; i < GS / 4; i += 256) {
        float4 v;
        v.x = row[cols[4 * i + 0]];
        v.y = row[cols[4 * i + 1]];
        v.z = row[cols[4 * i + 2]];
        v.w = row[cols[4 * i + 3]];
        out4[i] = v;
    }
}

extern "C" void kernel_launch(void* const* d_in, const int* in_sizes, int n_in,
                              void* d_out, int out_size, void* d_ws, size_t ws_size,
                              hipStream_t stream) {
    const float* A = (const float*)d_in[0];   // (8, 4096, 4096) fp32
    const float* x = (const float*)d_in[1];   // (8, 4096, 128)  fp32

    float* outA = (float*)d_out;                          // (8, 1024, 1024)
    float* outx = outA + (size_t)BB * GS * GS;            // (8, 1024, 128)

    int* idx = (int*)d_ws;                                // 8*1024 ints = 32 KB

    topk_kernel<<<BB, 1024, 0, stream>>>(x, idx);
    gatherx_kernel<<<(BB * GS * 32) / 256, 256, 0, stream>>>(x, idx, outx);
    gatherA_kernel<<<BB * GS, 256, 0, stream>>>(A, idx, outA);
}

// Round 2
// 658.982 us; speedup vs baseline: 1.0328x; 1.0328x over previous
//
#include <hip/hip_runtime.h>
#include <hip/hip_bf16.h>

#define BB 8
#define NN 4096
#define FF 128
#define GS 1024

// ---------------------------------------------------------------------------
// Kernel 1a: build sortable keys. key = (~sortable_asc(v) << 32) | i so that
// ascending key order == descending value, ties broken by ascending index
// (exact jax.lax.top_k semantics). Keys are all distinct (index in low bits).
// ---------------------------------------------------------------------------
__global__ __launch_bounds__(256) void keys_kernel(const float* __restrict__ x,
                                                   unsigned long long* __restrict__ keys) {
    int gid = blockIdx.x * 256 + threadIdx.x;      // [0, BB*NN)
    int b = gid >> 12;
    int i = gid & (NN - 1);
    float v = x[((size_t)b * NN + i) * FF + (FF - 1)];
    unsigned int bits = __float_as_uint(v);
    unsigned int sv = (bits & 0x80000000u) ? ~bits : (bits | 0x80000000u);
    keys[gid] = ((unsigned long long)(~sv) << 32) | (unsigned int)i;
}

// ---------------------------------------------------------------------------
// Kernel 1b: rank by counting. Each block stages its batch's 4096 keys in LDS
// (32 KB), each thread counts how many keys are smaller than its own -> that
// count IS its output position. rank < GS => idx[b*GS + rank] = index.
// All lanes scan the same LDS address per iteration -> broadcast, no bank
// conflicts. 16 blocks per batch, 128 blocks total.
// ---------------------------------------------------------------------------
__global__ __launch_bounds__(256) void rank_kernel(const unsigned long long* __restrict__ keys,
                                                   int* __restrict__ idx) {
    __shared__ unsigned long long lkeys[NN];       // 32 KB
    const int b = blockIdx.x >> 4;                 // 16 blocks per batch
    const int e = ((blockIdx.x & 15) << 8) + threadIdx.x;   // element in [0, NN)
    const unsigned long long* kb = keys + (size_t)b * NN;

    // coalesced 16B stage
    const ulonglong2* g2 = (const ulonglong2*)kb;
    ulonglong2*       l2 = (ulonglong2*)lkeys;
    for (int i = threadIdx.x; i < NN / 2; i += 256) l2[i] = g2[i];
    __syncthreads();

    const unsigned long long mk = lkeys[e];
    int cnt = 0;
    const ulonglong2* k2 = (const ulonglong2*)lkeys;
#pragma unroll 4
    for (int t = 0; t < NN / 2; t += 4) {
        ulonglong2 a = k2[t + 0];
        ulonglong2 c = k2[t + 1];
        ulonglong2 d = k2[t + 2];
        ulonglong2 f = k2[t + 3];
        cnt += (a.x < mk) + (a.y < mk) + (c.x < mk) + (c.y < mk)
             + (d.x < mk) + (d.y < mk) + (f.x < mk) + (f.y < mk);
    }
    if (cnt < GS) idx[b * GS + cnt] = (int)(mk & 0xFFFFFFFFu);
}

// ---------------------------------------------------------------------------
// Kernel 2: xg[b, j, :] = x[b, idx[b,j], :]  (32 lanes x float4 per row)
// ---------------------------------------------------------------------------
__global__ __launch_bounds__(256) void gatherx_kernel(const float* __restrict__ x,
                                                      const int* __restrict__ idx,
                                                      float* __restrict__ outx) {
    int gid  = blockIdx.x * 256 + threadIdx.x;     // B*GS*32 lanes total
    int lane = gid & 31;
    int row  = gid >> 5;                           // [0, B*GS)
    int b = row >> 10;
    int j = row & (GS - 1);
    int src = idx[b * GS + j];
    const float4* s4 = (const float4*)(x + ((size_t)b * NN + src) * FF);
    float4*       d4 = (float4*)(outx + (size_t)row * FF);
    d4[lane] = s4[lane];
}

// ---------------------------------------------------------------------------
// Kernel 3: At2[b, j, k] = A[b, idx[b,j], idx[b,k]].
// One block per output row: stage full 16 KB source row in LDS (coalesced),
// gather 1024 columns from LDS, write coalesced float4.
// ---------------------------------------------------------------------------
__global__ __launch_bounds__(256) void gatherA_kernel(const float* __restrict__ A,
                                                      const int* __restrict__ idx,
                                                      float* __restrict__ outA) {
    __shared__ float row[NN];    // 16 KB
    __shared__ int  cols[GS];    //  4 KB
    const int b = blockIdx.x >> 10;
    const int j = blockIdx.x & (GS - 1);
    const int* idxb = idx + b * GS;
    const int srcrow = idxb[j];

    const float4* a4   = (const float4*)(A + ((size_t)b * NN + srcrow) * NN);
    float4*       row4 = (float4*)row;
    for (int i = threadIdx.x; i < NN / 4; i += 256) row4[i] = a4[i];
    for (int i = threadIdx.x; i < GS; i += 256)     cols[i] = idxb[i];
    __syncthreads();

    float4* out4 = (float4*)(outA + (size_t)blockIdx.x * GS);
    for (int i = threadIdx.x; i < GS / 4; i += 256) {
        float4 v;
        v.x = row[cols[4 * i + 0]];
        v.y = row[cols[4 * i + 1]];
        v.z = row[cols[4 * i + 2]];
        v.w = row[cols[4 * i + 3]];
        out4[i] = v;
    }
}

extern "C" void kernel_launch(void* const* d_in, const int* in_sizes, int n_in,
                              void* d_out, int out_size, void* d_ws, size_t ws_size,
                              hipStream_t stream) {
    const float* A = (const float*)d_in[0];   // (8, 4096, 4096) fp32
    const float* x = (const float*)d_in[1];   // (8, 4096, 128)  fp32

    float* outA = (float*)d_out;                          // (8, 1024, 1024)
    float* outx = outA + (size_t)BB * GS * GS;            // (8, 1024, 128)

    int* idx = (int*)d_ws;                                          // 32 KB
    unsigned long long* keys = (unsigned long long*)((char*)d_ws + 64 * 1024); // 256 KB

    keys_kernel<<<(BB * NN) / 256, 256, 0, stream>>>(x, keys);
    rank_kernel<<<(BB * NN) / 256, 256, 0, stream>>>(keys, idx);
    gatherx_kernel<<<(BB * GS * 32) / 256, 256, 0, stream>>>(x, idx, outx);
    gatherA_kernel<<<BB * GS, 256, 0, stream>>>(A, idx, outA);
}